// Round 1
// baseline (1099.143 us; speedup 1.0000x reference)
//
#include <hip/hip_runtime.h>
#include <float.h>

// Quantize: z [8,4096,512] f32, embed_w [512,128] f32, GROUPS=4
// flat = z.reshape(131072, 128); dist to 512 codes; argmin; gather; MSE scalar.
// Outputs concatenated in d_out (f32): z_q_st [16777216], diff [1], ind [131072] (as float)

constexpr int Dn = 128;          // sub-vector dim
constexpr int K  = 512;          // codebook entries
constexpr long long Mrows = 131072;
constexpr int BM = 64;           // rows per block
constexpr int BN = 128;          // codes per chunk
constexpr int NCHUNK = K / BN;   // 4
constexpr int TM = 4;            // rows per thread
constexpr int TN = 8;            // codes per thread per chunk
constexpr float TAU = 0.02f;     // fp32 margin below which we re-solve in fp64

constexpr size_t ZQ_SIZE  = (size_t)Mrows * Dn;   // 16777216
constexpr size_t DIFF_OFF = ZQ_SIZE;
constexpr size_t IND_OFF  = ZQ_SIZE + 1;

__global__ void wnorm_kernel(const float* __restrict__ W, float* __restrict__ wn) {
    int k = blockIdx.x * blockDim.x + threadIdx.x;
    if (k < K) {
        double s = 0.0;
        const float* w = W + (size_t)k * Dn;
        #pragma unroll 4
        for (int i = 0; i < Dn; ++i) { double v = (double)w[i]; s += v * v; }
        wn[k] = (float)s;
    }
}

__global__ __launch_bounds__(256) void vq_main(
        const float* __restrict__ Z, const float* __restrict__ W,
        const float* __restrict__ wn, float* __restrict__ out,
        double* __restrict__ diffsum) {
    // X tile, XOR-swizzled in 16B units: chunk c stored at c ^ (row & 3)
    __shared__ float Xs[BM][Dn];
    __shared__ int   sIdx[BM];
    __shared__ int   sFlag[BM];
    __shared__ float wpart[4];

    const int tid = threadIdx.x;
    const int tx = tid & 15, ty = tid >> 4;
    const size_t row0 = (size_t)blockIdx.x * BM;

    // ---- stage X tile (coalesced float4, swizzled LDS write) ----
    {
        const float4* src = (const float4*)(Z + row0 * Dn);
        #pragma unroll
        for (int t = 0; t < 8; ++t) {
            int i = tid + t * 256;         // float4 index in tile, 0..2047
            int row = i >> 5;              // /32 float4 per row
            int c = i & 31;
            float4 v = src[i];
            *(float4*)&Xs[row][(c ^ (row & 3)) << 2] = v;
        }
    }
    __syncthreads();

    // ---- distance GEMM + per-row (min1, idx, min2) tracking ----
    float m1[TM], m2[TM];
    int i1[TM];
    #pragma unroll
    for (int r = 0; r < TM; ++r) { m1[r] = FLT_MAX; m2[r] = FLT_MAX; i1[r] = 0; }

    for (int ch = 0; ch < NCHUNK; ++ch) {
        const int cbase = ch * BN;
        float acc[TM][TN];
        #pragma unroll
        for (int r = 0; r < TM; ++r)
            #pragma unroll
            for (int j = 0; j < TN; ++j) acc[r][j] = 0.f;

        #pragma unroll 4
        for (int dd = 0; dd < Dn; dd += 4) {
            const int c4 = dd >> 2;
            float4 xv[TM];
            #pragma unroll
            for (int r = 0; r < TM; ++r) {
                const int row = ty + 16 * r;
                xv[r] = *(const float4*)&Xs[row][(c4 ^ (row & 3)) << 2];
            }
            #pragma unroll
            for (int j = 0; j < TN; ++j) {
                const float4 wv = *(const float4*)&W[(size_t)(cbase + tx + 16 * j) * Dn + dd];
                #pragma unroll
                for (int r = 0; r < TM; ++r) {
                    acc[r][j] += xv[r].x * wv.x;
                    acc[r][j] += xv[r].y * wv.y;
                    acc[r][j] += xv[r].z * wv.z;
                    acc[r][j] += xv[r].w * wv.w;
                }
            }
        }
        // fold chunk scores into running min pair (score = ||w||^2 - 2 x.w; ||x||^2 constant per row)
        #pragma unroll
        for (int j = 0; j < TN; ++j) {
            const int c = cbase + tx + 16 * j;
            const float wnv = wn[c];
            #pragma unroll
            for (int r = 0; r < TM; ++r) {
                float s = wnv - 2.f * acc[r][j];
                if (s < m1[r]) { m2[r] = m1[r]; m1[r] = s; i1[r] = c; }
                else if (s < m2[r]) m2[r] = s;
            }
        }
    }

    // ---- reduce (min1, idx, min2) across the 16 tx lanes ----
    #pragma unroll
    for (int sft = 1; sft < 16; sft <<= 1) {
        #pragma unroll
        for (int r = 0; r < TM; ++r) {
            float o1 = __shfl_xor(m1[r], sft);
            float o2 = __shfl_xor(m2[r], sft);
            int   oi = __shfl_xor(i1[r], sft);
            if (o1 < m1[r] || (o1 == m1[r] && oi < i1[r])) {
                m2[r] = fminf(m1[r], o2);
                m1[r] = o1;
                i1[r] = oi;
            } else {
                m2[r] = fminf(m2[r], o1);
            }
        }
    }
    if (tx == 0) {
        #pragma unroll
        for (int r = 0; r < TM; ++r) {
            const int row = ty + 16 * r;
            sIdx[row]  = i1[r];
            sFlag[row] = (m2[r] - m1[r] < TAU) ? 1 : 0;
        }
    }
    __syncthreads();

    // ---- fp64 refinement of near-tie rows (rare: ~1e-3 of rows) ----
    const int wave = tid >> 6, lane = tid & 63;
    for (int rr = wave * 16; rr < wave * 16 + 16; ++rr) {
        if (!sFlag[rr]) continue;            // wave-uniform (same LDS word)
        double best = 1e300; int bi = 0;
        for (int j = 0; j < 8; ++j) {
            const int k = lane + 64 * j;
            const float* w = W + (size_t)k * Dn;
            double s = 0.0;
            for (int i = 0; i < Dn; ++i) {
                const int c4 = i >> 2;
                const float xv = Xs[rr][((c4 ^ (rr & 3)) << 2) | (i & 3)];
                const double dx = (double)xv - (double)w[i];
                s += dx * dx;
            }
            if (s < best) { best = s; bi = k; }   // ascending k => first-occurrence tie-break
        }
        #pragma unroll
        for (int sft = 1; sft < 64; sft <<= 1) {
            double ob = __shfl_xor(best, sft);
            int    ok = __shfl_xor(bi, sft);
            if (ob < best || (ob == best && ok < bi)) { best = ob; bi = ok; }
        }
        if (lane == 0) sIdx[rr] = bi;
    }
    __syncthreads();

    // ---- epilogue: gather codebook row, straight-through output, MSE partial ----
    float psum = 0.f;
    {
        const int row = tid >> 2, q = tid & 3;   // 4 threads per row, 32 floats each
        const int ind = sIdx[row];
        const float* w = W + (size_t)ind * Dn;
        float* dst = out + (row0 + row) * (size_t)Dn;
        #pragma unroll
        for (int c4 = q * 8; c4 < q * 8 + 8; ++c4) {
            const float4 xv = *(const float4*)&Xs[row][(c4 ^ (row & 3)) << 2];
            const float4 wv = *(const float4*)&w[c4 << 2];
            float dx0 = wv.x - xv.x, dx1 = wv.y - xv.y, dx2 = wv.z - xv.z, dx3 = wv.w - xv.w;
            float4 o;
            o.x = xv.x + dx0; o.y = xv.y + dx1; o.z = xv.z + dx2; o.w = xv.w + dx3;
            *(float4*)&dst[c4 << 2] = o;
            psum += dx0 * dx0 + dx1 * dx1 + dx2 * dx2 + dx3 * dx3;
        }
    }
    if (tid < BM) out[IND_OFF + row0 + tid] = (float)sIdx[tid];

    #pragma unroll
    for (int sft = 1; sft < 64; sft <<= 1) psum += __shfl_xor(psum, sft);
    if (lane == 0) wpart[wave] = psum;
    __syncthreads();
    if (tid == 0) {
        double t = (double)wpart[0] + (double)wpart[1] + (double)wpart[2] + (double)wpart[3];
        atomicAdd(diffsum, t);
    }
}

__global__ void diff_kernel(const double* __restrict__ diffsum, float* __restrict__ out) {
    if (threadIdx.x == 0 && blockIdx.x == 0) {
        // KLD_SCALE * (COMMITMENT_COST * mean + mean) = 10 * 1.25 * mean
        out[DIFF_OFF] = (float)(12.5 * diffsum[0] / (double)ZQ_SIZE);
    }
}

extern "C" void kernel_launch(void* const* d_in, const int* in_sizes, int n_in,
                              void* d_out, int out_size, void* d_ws, size_t ws_size,
                              hipStream_t stream) {
    (void)in_sizes; (void)n_in; (void)out_size; (void)ws_size;
    const float* Z = (const float*)d_in[0];
    const float* W = (const float*)d_in[1];
    float* out = (float*)d_out;
    double* diffsum = (double*)d_ws;
    float* wn = (float*)((char*)d_ws + 16);

    hipMemsetAsync(d_ws, 0, 16, stream);
    wnorm_kernel<<<2, 256, 0, stream>>>(W, wn);
    vq_main<<<(int)(Mrows / BM), 256, 0, stream>>>(Z, W, wn, out, diffsum);
    diff_kernel<<<1, 64, 0, stream>>>(diffsum, out);
}

// Round 2
// 167.265 us; speedup vs baseline: 6.5713x; 6.5713x over previous
//
#include <hip/hip_runtime.h>
#include <float.h>

// Quantize: z [8,4096,512] f32, embed_w [512,128] f32, GROUPS=4
// flat = z.reshape(131072,128); dist to 512 codes; argmin; gather; MSE scalar.
// d_out (f32): z_q_st [16777216], diff [1], ind [131072] (as float).
// Strategy: bf16 split-precision MFMA (hi*hi + lo*hi + hi*lo), fp64 exact
// refinement for rows whose top-2 score margin < TAU.

typedef __attribute__((ext_vector_type(8))) short short8;
typedef __attribute__((ext_vector_type(4))) float f32x4;

constexpr int Dn = 128;
constexpr int K  = 512;
constexpr long long Mrows = 131072;
constexpr int ROWS_PER_BLOCK = 128;                 // 4 waves x 32 rows
constexpr int NBLK = (int)(Mrows / ROWS_PER_BLOCK); // 1024
constexpr int CHUNK = 64;                           // codes per LDS chunk
constexpr int NCH = K / CHUNK;                      // 8
constexpr float TAU = 0.02f;                        // >> 2*(bf16-split score error ~1e-3)

constexpr size_t ZQ_SIZE  = (size_t)Mrows * Dn;     // 16777216
constexpr size_t DIFF_OFF = ZQ_SIZE;
constexpr size_t IND_OFF  = ZQ_SIZE + 1;

__device__ inline unsigned short f2bf(float f) {    // RNE float->bf16
    unsigned u = __builtin_bit_cast(unsigned, f);
    u += 0x7FFFu + ((u >> 16) & 1u);
    return (unsigned short)(u >> 16);
}
__device__ inline float bf2f(unsigned short s) {
    unsigned u = ((unsigned)s) << 16;
    return __builtin_bit_cast(float, u);
}

__global__ void wnorm_kernel(const float* __restrict__ W, float* __restrict__ wn) {
    int k = blockIdx.x * blockDim.x + threadIdx.x;
    if (k < K) {
        double s = 0.0;
        const float* w = W + (size_t)k * Dn;
        #pragma unroll 4
        for (int i = 0; i < Dn; ++i) { double v = (double)w[i]; s += v * v; }
        wn[k] = (float)s;
    }
}

__global__ __launch_bounds__(256) void vq_main(
        const float* __restrict__ Z, const float* __restrict__ W,
        const float* __restrict__ wn, float* __restrict__ out,
        double* __restrict__ diffsum) {
    // W chunk, bf16 hi/lo, XOR-swizzled in 16B granules: g' = g ^ (code&7)
    __shared__ unsigned short Whi_s[CHUNK * Dn];   // 16 KB
    __shared__ unsigned short Wlo_s[CHUNK * Dn];   // 16 KB
    __shared__ int   sIdx[ROWS_PER_BLOCK];
    __shared__ int   sFlag[ROWS_PER_BLOCK];
    __shared__ float xn_s[ROWS_PER_BLOCK];
    __shared__ float wpart[4];

    const int tid  = threadIdx.x;
    const int w    = tid >> 6;
    const int lane = tid & 63;
    const int lm   = lane & 15;        // row (A) / col (B) within 16-tile
    const int lg   = lane >> 4;        // k-block (0..3)
    const size_t row0 = (size_t)blockIdx.x * ROWS_PER_BLOCK;

    // ---- X fragments (hi/lo bf16) + row norms, all in registers ----
    // A-frag (16x16x32): lane lm = row, k = lg*8 + j (8 contiguous dims)
    short8 ahi[2][4], alo[2][4];
    #pragma unroll
    for (int r = 0; r < 2; ++r) {
        const size_t grow = row0 + (size_t)w * 32 + r * 16 + lm;
        float s2 = 0.f;
        #pragma unroll
        for (int ks = 0; ks < 4; ++ks) {
            const float* xp = Z + grow * Dn + ks * 32 + lg * 8;
            float4 x0 = *(const float4*)xp;
            float4 x1 = *(const float4*)(xp + 4);
            float xv[8] = {x0.x, x0.y, x0.z, x0.w, x1.x, x1.y, x1.z, x1.w};
            #pragma unroll
            for (int j = 0; j < 8; ++j) {
                unsigned short hs = f2bf(xv[j]);
                float lo = xv[j] - bf2f(hs);
                ahi[r][ks][j] = (short)hs;
                alo[r][ks][j] = (short)f2bf(lo);
                s2 += xv[j] * xv[j];
            }
        }
        s2 += __shfl_xor(s2, 16);
        s2 += __shfl_xor(s2, 32);      // full ||x||^2 for row grow
        if (lg == 0) xn_s[w * 32 + r * 16 + lm] = s2;
    }

    // ---- per-lane (min1, idx, min2) over all 512 codes ----
    float m1[2][4], m2[2][4];
    int   i1[2][4];
    #pragma unroll
    for (int r = 0; r < 2; ++r)
        #pragma unroll
        for (int j = 0; j < 4; ++j) { m1[r][j] = FLT_MAX; m2[r][j] = FLT_MAX; i1[r][j] = 0; }

    for (int ch = 0; ch < NCH; ++ch) {
        __syncthreads();               // previous chunk fully consumed
        // stage chunk: 64 codes x 128 dims fp32 -> bf16 hi/lo, swizzled LDS
        {
            const float4* wsrc = (const float4*)(W + (size_t)ch * CHUNK * Dn);
            #pragma unroll
            for (int it = 0; it < 8; ++it) {
                int f4i  = tid + it * 256;     // 0..2047
                int code = f4i >> 5;           // 32 float4 per code row
                int q    = f4i & 31;
                float4 v = wsrc[f4i];
                float vv[4] = {v.x, v.y, v.z, v.w};
                ushort4 h4, l4;
                unsigned short* hp = (unsigned short*)&h4;
                unsigned short* lp = (unsigned short*)&l4;
                #pragma unroll
                for (int e = 0; e < 4; ++e) {
                    unsigned short hs = f2bf(vv[e]);
                    hp[e] = hs;
                    lp[e] = f2bf(vv[e] - bf2f(hs));
                }
                int off = code * 256 + (((q >> 1) ^ (code & 7)) << 4) + (q & 1) * 8;
                *(ushort4*)((char*)Whi_s + off) = h4;
                *(ushort4*)((char*)Wlo_s + off) = l4;
            }
        }
        __syncthreads();

        #pragma unroll
        for (int t = 0; t < 4; ++t) {          // 16-code column tiles
            const int code_l = t * 16 + lm;    // code within chunk (B col)
            short8 bhi[4], blo[4];
            #pragma unroll
            for (int ks = 0; ks < 4; ++ks) {
                int off = code_l * 256 + ((((ks << 2) + lg) ^ (code_l & 7)) << 4);
                bhi[ks] = *(const short8*)((char*)Whi_s + off);
                blo[ks] = *(const short8*)((char*)Wlo_s + off);
            }
            f32x4 acc[2] = {{0.f,0.f,0.f,0.f},{0.f,0.f,0.f,0.f}};
            #pragma unroll
            for (int ks = 0; ks < 4; ++ks) {
                #pragma unroll
                for (int r = 0; r < 2; ++r) {
                    acc[r] = __builtin_amdgcn_mfma_f32_16x16x32_bf16(ahi[r][ks], bhi[ks], acc[r], 0, 0, 0);
                    acc[r] = __builtin_amdgcn_mfma_f32_16x16x32_bf16(alo[r][ks], bhi[ks], acc[r], 0, 0, 0);
                    acc[r] = __builtin_amdgcn_mfma_f32_16x16x32_bf16(ahi[r][ks], blo[ks], acc[r], 0, 0, 0);
                }
            }
            const int   c   = ch * CHUNK + t * 16 + lm;
            const float wnv = wn[c];
            #pragma unroll
            for (int r = 0; r < 2; ++r) {
                #pragma unroll
                for (int j = 0; j < 4; ++j) {
                    float s  = fmaf(-2.f, acc[r][j], wnv);   // ||w||^2 - 2 x.w
                    bool  lt = s < m1[r][j];
                    m2[r][j] = fminf(m2[r][j], fmaxf(s, m1[r][j]));
                    m1[r][j] = fminf(m1[r][j], s);
                    i1[r][j] = lt ? c : i1[r][j];
                }
            }
        }
    }

    // ---- reduce (m1, idx, m2) across the 16 col-lanes (xor 1,2,4,8) ----
    #pragma unroll
    for (int sft = 1; sft < 16; sft <<= 1) {
        #pragma unroll
        for (int r = 0; r < 2; ++r) {
            #pragma unroll
            for (int j = 0; j < 4; ++j) {
                float o1 = __shfl_xor(m1[r][j], sft);
                float o2 = __shfl_xor(m2[r][j], sft);
                int   oi = __shfl_xor(i1[r][j], sft);
                if (o1 < m1[r][j] || (o1 == m1[r][j] && oi < i1[r][j])) {
                    m2[r][j] = fminf(m1[r][j], o2);
                    m1[r][j] = o1;
                    i1[r][j] = oi;
                } else {
                    m2[r][j] = fminf(m2[r][j], o1);
                }
            }
        }
    }

    float psum = 0.f;
    if (lm == 0) {
        #pragma unroll
        for (int r = 0; r < 2; ++r) {
            #pragma unroll
            for (int j = 0; j < 4; ++j) {
                const int row = w * 32 + r * 16 + lg * 4 + j;   // C row = lg*4 + reg
                sIdx[row]  = i1[r][j];
                sFlag[row] = (m2[r][j] - m1[r][j] < TAU) ? 1 : 0;
                psum += m1[r][j] + xn_s[row];   // ||x - w||^2 = (||w||^2 - 2x.w) + ||x||^2
            }
        }
    }
    __syncthreads();

    // ---- fp64 exact refinement of near-tie rows (rare) ----
    {
        const int rbase = w * 32;
        for (int rr = rbase; rr < rbase + 32; ++rr) {
            if (!sFlag[rr]) continue;          // wave-uniform
            const float* xp = Z + (row0 + rr) * Dn;
            double best = 1e300; int bi = 0;
            for (int jj = 0; jj < 8; ++jj) {
                const int k = lane + 64 * jj;
                const float* wp = W + (size_t)k * Dn;
                double s = 0.0;
                for (int i = 0; i < Dn; ++i) {
                    double dx = (double)xp[i] - (double)wp[i];
                    s += dx * dx;
                }
                if (s < best) { best = s; bi = k; }
            }
            #pragma unroll
            for (int sft = 1; sft < 64; sft <<= 1) {
                double ob = __shfl_xor(best, sft);
                int    ok = __shfl_xor(bi, sft);
                if (ob < best || (ob == best && ok < bi)) { best = ob; bi = ok; }
            }
            if (lane == 0) sIdx[rr] = bi;
        }
    }
    __syncthreads();

    // ---- epilogue: z_q_st == W[ind] gather; indices; diff partial ----
    #pragma unroll
    for (int it = 0; it < 16; ++it) {
        int f4i = tid + it * 256;              // 0..4095
        int row = f4i >> 5, cq = f4i & 31;
        int ind = sIdx[row];
        float4 wv = ((const float4*)(W + (size_t)ind * Dn))[cq];
        ((float4*)(out + (row0 + row) * Dn))[cq] = wv;
    }
    if (tid < ROWS_PER_BLOCK) out[IND_OFF + row0 + tid] = (float)sIdx[tid];

    #pragma unroll
    for (int sft = 1; sft < 64; sft <<= 1) psum += __shfl_xor(psum, sft);
    if (lane == 0) wpart[w] = psum;
    __syncthreads();
    if (tid == 0) {
        double t = (double)wpart[0] + (double)wpart[1] + (double)wpart[2] + (double)wpart[3];
        atomicAdd(diffsum, t);
    }
}

__global__ void diff_kernel(const double* __restrict__ diffsum, float* __restrict__ out) {
    if (threadIdx.x == 0 && blockIdx.x == 0) {
        // KLD_SCALE * (COMMITMENT_COST + 1) * mean = 12.5 * mean
        out[DIFF_OFF] = (float)(12.5 * diffsum[0] / (double)ZQ_SIZE);
    }
}

extern "C" void kernel_launch(void* const* d_in, const int* in_sizes, int n_in,
                              void* d_out, int out_size, void* d_ws, size_t ws_size,
                              hipStream_t stream) {
    (void)in_sizes; (void)n_in; (void)out_size; (void)ws_size;
    const float* Z = (const float*)d_in[0];
    const float* W = (const float*)d_in[1];
    float* out = (float*)d_out;
    double* diffsum = (double*)d_ws;
    float* wn = (float*)((char*)d_ws + 16);

    hipMemsetAsync(d_ws, 0, 16, stream);
    wnorm_kernel<<<2, 256, 0, stream>>>(W, wn);
    vq_main<<<NBLK, 256, 0, stream>>>(Z, W, wn, out, diffsum);
    diff_kernel<<<1, 64, 0, stream>>>(diffsum, out);
}

// Round 3
// 162.631 us; speedup vs baseline: 6.7585x; 1.0285x over previous
//
#include <hip/hip_runtime.h>
#include <float.h>

// Quantize: z [8,4096,512] f32, embed_w [512,128] f32, GROUPS=4
// flat = z.reshape(131072,128); dist to 512 codes; argmin; gather; MSE scalar.
// d_out (f32): z_q_st [16777216], diff [1], ind [131072] (as float).
//
// Strategy: bf16 split-precision MFMA (hi*hi + lo*hi + hi*lo) with
//  - W preconverted to bf16 hi/lo ONCE (prep kernel), pre-swizzled so
//    global_load_lds (linear dest) + swizzled ds_read are conflict-reduced
//  - double-buffered chunk staging (issue DMA -> compute -> vmcnt(0)+barrier)
//  - ||w||^2 folded into MFMA C-init: track max of (dot - 0.5*||w||^2)
//  - fp64 exact refinement for rows whose top-2 margin < TAU  => exact argmin

typedef __attribute__((ext_vector_type(8))) short short8;
typedef __attribute__((ext_vector_type(4))) float f32x4;

constexpr int Dn = 128;
constexpr int K  = 512;
constexpr long long Mrows = 131072;
constexpr int RPB  = 128;                    // rows per block (4 waves x 32)
constexpr int NBLK = (int)(Mrows / RPB);     // 1024
constexpr int CHUNK = 64;                    // codes per LDS chunk
constexpr int NCH   = K / CHUNK;             // 8
constexpr float TAU = 0.02f;                 // fp32-score margin for fp64 re-solve

constexpr size_t ZQ_SIZE  = (size_t)Mrows * Dn;
constexpr size_t DIFF_OFF = ZQ_SIZE;
constexpr size_t IND_OFF  = ZQ_SIZE + 1;

__device__ inline unsigned short f2bf(float f) {    // RNE float->bf16
    unsigned u = __builtin_bit_cast(unsigned, f);
    u += 0x7FFFu + ((u >> 16) & 1u);
    return (unsigned short)(u >> 16);
}
__device__ inline float bf2f(unsigned short s) {
    unsigned u = ((unsigned)s) << 16;
    return __builtin_bit_cast(float, u);
}

__device__ inline void gload_lds16(const void* g, void* l) {
    __builtin_amdgcn_global_load_lds(
        (const __attribute__((address_space(1))) unsigned int*)g,
        (__attribute__((address_space(3))) unsigned int*)l,
        16, 0, 0);
}

__global__ void wnorm_kernel(const float* __restrict__ W, float* __restrict__ wn) {
    int k = blockIdx.x * blockDim.x + threadIdx.x;
    if (k < K) {
        double s = 0.0;
        const float* w = W + (size_t)k * Dn;
        #pragma unroll 4
        for (int i = 0; i < Dn; ++i) { double v = (double)w[i]; s += v * v; }
        wn[k] = (float)s;
    }
}

// W -> bf16 hi/lo, pre-swizzled granule order.
// Per chunk ch (64 codes): 32 KB = [hi 16KB][lo 16KB].
// Granule index within hi region: G = code_l*16 + gs; holds physical granule
// g = gs ^ (code_l & 7) of that code's 128-dim row (8 bf16 per granule).
__global__ void prep_kernel(const float* __restrict__ W, unsigned short* __restrict__ Wp) {
    int t = blockIdx.x * 256 + threadIdx.x;  // 0..8191 (512 codes * 16 granules)
    int ch     = t >> 10;
    int G      = t & 1023;
    int code_l = G >> 4;
    int gs     = G & 15;
    int g      = gs ^ (code_l & 7);
    int code   = ch * CHUNK + code_l;
    const float* src = W + (size_t)code * Dn + g * 8;
    ushort4 h[2], l[2];
    #pragma unroll
    for (int half = 0; half < 2; ++half) {
        float4 v = *(const float4*)(src + half * 4);
        float vv[4] = {v.x, v.y, v.z, v.w};
        unsigned short* hp = (unsigned short*)&h[half];
        unsigned short* lp = (unsigned short*)&l[half];
        #pragma unroll
        for (int e = 0; e < 4; ++e) {
            unsigned short hs = f2bf(vv[e]);
            hp[e] = hs;
            lp[e] = f2bf(vv[e] - bf2f(hs));
        }
    }
    size_t base = (size_t)ch * 16384 + (size_t)G * 8;   // ushort units
    *(ushort4*)(Wp + base)            = h[0];
    *(ushort4*)(Wp + base + 4)        = h[1];
    *(ushort4*)(Wp + base + 8192)     = l[0];
    *(ushort4*)(Wp + base + 8192 + 4) = l[1];
}

__global__ __launch_bounds__(256) void vq_main(
        const float* __restrict__ Z, const float* __restrict__ W,
        const unsigned short* __restrict__ Wp, const float* __restrict__ wn,
        float* __restrict__ out, double* __restrict__ diffsum) {
    __shared__ __align__(16) char Wbuf[2][32768];   // double-buffered chunk (hi+lo)
    __shared__ int   sIdx[RPB];
    __shared__ int   sFlag[RPB];
    __shared__ float xn_s[RPB];
    __shared__ float wpart[4];

    const int tid  = threadIdx.x;
    const int w    = tid >> 6;
    const int lane = tid & 63;
    const int lm   = lane & 15;        // A row / B col within 16-tile
    const int lg   = lane >> 4;        // k-block (0..3)
    const size_t row0 = (size_t)blockIdx.x * RPB;

    // ---- X fragments (hi/lo bf16) + exact row norms, in registers ----
    short8 ahi[2][4], alo[2][4];
    #pragma unroll
    for (int r = 0; r < 2; ++r) {
        const size_t grow = row0 + (size_t)w * 32 + r * 16 + lm;
        float s2 = 0.f;
        #pragma unroll
        for (int ks = 0; ks < 4; ++ks) {
            const float* xp = Z + grow * Dn + ks * 32 + lg * 8;
            float4 x0 = *(const float4*)xp;
            float4 x1 = *(const float4*)(xp + 4);
            float xv[8] = {x0.x, x0.y, x0.z, x0.w, x1.x, x1.y, x1.z, x1.w};
            #pragma unroll
            for (int j = 0; j < 8; ++j) {
                unsigned short hs = f2bf(xv[j]);
                ahi[r][ks][j] = (short)hs;
                alo[r][ks][j] = (short)f2bf(xv[j] - bf2f(hs));
                s2 += xv[j] * xv[j];
            }
        }
        s2 += __shfl_xor(s2, 16);
        s2 += __shfl_xor(s2, 32);
        if (lg == 0) xn_s[w * 32 + r * 16 + lm] = s2;
    }

    // ---- staging: pure DMA copy (layout already swizzled in Wp) ----
    auto stage = [&](int bi, int ch) {
        const char* gsrc = (const char*)Wp + (size_t)ch * 32768;
        char* lb = &Wbuf[bi][0];
        #pragma unroll
        for (int it = 0; it < 8; ++it) {
            const int gb = (w * 8 + it) * 64;            // wave-uniform granule base
            gload_lds16(gsrc + (size_t)(gb + lane) * 16, lb + (size_t)gb * 16);
        }
    };

    // max-tracking of a = dot - 0.5*||w||^2  (argmin dist == argmax a)
    float m1[2][4], m2[2][4];
    int   i1[2][4];
    #pragma unroll
    for (int r = 0; r < 2; ++r)
        #pragma unroll
        for (int j = 0; j < 4; ++j) { m1[r][j] = -FLT_MAX; m2[r][j] = -FLT_MAX; i1[r][j] = 0; }

    stage(0, 0);
    asm volatile("s_waitcnt vmcnt(0)" ::: "memory");
    __syncthreads();

    for (int ch = 0; ch < NCH; ++ch) {
        const int cur = ch & 1;
        if (ch + 1 < NCH) stage(cur ^ 1, ch + 1);     // prefetch next chunk (async)
        const char* buf = &Wbuf[cur][0];

        #pragma unroll
        for (int t = 0; t < 4; ++t) {
            const int code_l = t * 16 + lm;
            const int c = ch * CHUNK + code_l;
            const float cinit = -0.5f * wn[c];
            short8 bhi[4], blo[4];
            #pragma unroll
            for (int ks = 0; ks < 4; ++ks) {
                const int off = code_l * 256 + ((((ks << 2) + lg) ^ (code_l & 7)) << 4);
                bhi[ks] = *(const short8*)(buf + off);
                blo[ks] = *(const short8*)(buf + 16384 + off);
            }
            f32x4 acc[2];
            #pragma unroll
            for (int r = 0; r < 2; ++r) acc[r] = (f32x4){cinit, cinit, cinit, cinit};
            #pragma unroll
            for (int ks = 0; ks < 4; ++ks) {
                #pragma unroll
                for (int r = 0; r < 2; ++r) {
                    acc[r] = __builtin_amdgcn_mfma_f32_16x16x32_bf16(ahi[r][ks], bhi[ks], acc[r], 0, 0, 0);
                    acc[r] = __builtin_amdgcn_mfma_f32_16x16x32_bf16(alo[r][ks], bhi[ks], acc[r], 0, 0, 0);
                    acc[r] = __builtin_amdgcn_mfma_f32_16x16x32_bf16(ahi[r][ks], blo[ks], acc[r], 0, 0, 0);
                }
            }
            #pragma unroll
            for (int r = 0; r < 2; ++r) {
                #pragma unroll
                for (int j = 0; j < 4; ++j) {
                    const float a = acc[r][j];
                    m2[r][j] = __builtin_amdgcn_fmed3f(a, m1[r][j], m2[r][j]);
                    const bool gt = a > m1[r][j];
                    m1[r][j] = fmaxf(m1[r][j], a);
                    i1[r][j] = gt ? c : i1[r][j];
                }
            }
        }
        asm volatile("s_waitcnt vmcnt(0)" ::: "memory");  // next chunk landed
        __syncthreads();                                   // all waves done with buf
    }

    // ---- reduce (m1, idx, m2) across the 16 col-lanes ----
    #pragma unroll
    for (int sft = 1; sft < 16; sft <<= 1) {
        #pragma unroll
        for (int r = 0; r < 2; ++r) {
            #pragma unroll
            for (int j = 0; j < 4; ++j) {
                float o1 = __shfl_xor(m1[r][j], sft);
                float o2 = __shfl_xor(m2[r][j], sft);
                int   oi = __shfl_xor(i1[r][j], sft);
                if (o1 > m1[r][j] || (o1 == m1[r][j] && oi < i1[r][j])) {
                    m2[r][j] = fmaxf(m1[r][j], o2);
                    m1[r][j] = o1;
                    i1[r][j] = oi;
                } else {
                    m2[r][j] = fmaxf(m2[r][j], o1);
                }
            }
        }
    }

    float psum = 0.f;
    if (lm == 0) {
        #pragma unroll
        for (int r = 0; r < 2; ++r) {
            #pragma unroll
            for (int j = 0; j < 4; ++j) {
                const int row = w * 32 + r * 16 + lg * 4 + j;   // C row = lg*4 + reg
                sIdx[row]  = i1[r][j];
                sFlag[row] = (m1[r][j] - m2[r][j] < 0.5f * TAU) ? 1 : 0;
                // dist^2 = ||x||^2 + (||w||^2 - 2 x.w) = xn - 2*a
                psum += xn_s[row] - 2.f * m1[r][j];
            }
        }
    }
    __syncthreads();

    // ---- fp64 exact refinement of near-tie rows (rare) ----
    {
        const int rbase = w * 32;
        for (int rr = rbase; rr < rbase + 32; ++rr) {
            if (!sFlag[rr]) continue;          // wave-uniform
            const float* xp = Z + (row0 + rr) * Dn;
            double best = 1e300; int bi = 0;
            for (int jj = 0; jj < 8; ++jj) {
                const int k = lane + 64 * jj;
                const float* wp = W + (size_t)k * Dn;
                double s = 0.0;
                for (int i = 0; i < Dn; ++i) {
                    double dx = (double)xp[i] - (double)wp[i];
                    s += dx * dx;
                }
                if (s < best) { best = s; bi = k; }
            }
            #pragma unroll
            for (int sft = 1; sft < 64; sft <<= 1) {
                double ob = __shfl_xor(best, sft);
                int    ok = __shfl_xor(bi, sft);
                if (ob < best || (ob == best && ok < bi)) { best = ob; bi = ok; }
            }
            if (lane == 0) sIdx[rr] = bi;
        }
    }
    __syncthreads();

    // ---- epilogue: z_q_st == W[ind] gather; indices; diff partial ----
    #pragma unroll
    for (int it = 0; it < 16; ++it) {
        int f4i = tid + it * 256;              // 0..4095
        int row = f4i >> 5, cq = f4i & 31;
        int ind = sIdx[row];
        float4 wv = ((const float4*)(W + (size_t)ind * Dn))[cq];
        ((float4*)(out + (row0 + row) * Dn))[cq] = wv;
    }
    if (tid < RPB) out[IND_OFF + row0 + tid] = (float)sIdx[tid];

    #pragma unroll
    for (int sft = 1; sft < 64; sft <<= 1) psum += __shfl_xor(psum, sft);
    if (lane == 0) wpart[w] = psum;
    __syncthreads();
    if (tid == 0) {
        double t = (double)wpart[0] + (double)wpart[1] + (double)wpart[2] + (double)wpart[3];
        atomicAdd(diffsum, t);
    }
}

__global__ void diff_kernel(const double* __restrict__ diffsum, float* __restrict__ out) {
    if (threadIdx.x == 0 && blockIdx.x == 0) {
        // KLD_SCALE * (COMMITMENT_COST + 1) * mean = 12.5 * mean
        out[DIFF_OFF] = (float)(12.5 * diffsum[0] / (double)ZQ_SIZE);
    }
}

extern "C" void kernel_launch(void* const* d_in, const int* in_sizes, int n_in,
                              void* d_out, int out_size, void* d_ws, size_t ws_size,
                              hipStream_t stream) {
    (void)in_sizes; (void)n_in; (void)out_size; (void)ws_size;
    const float* Z = (const float*)d_in[0];
    const float* W = (const float*)d_in[1];
    float* out = (float*)d_out;
    // ws layout: [0,8) diffsum double; [16,2064) wn f32[512]; [4096, 4096+256KB) Wp
    double* diffsum = (double*)d_ws;
    float* wn = (float*)((char*)d_ws + 16);
    unsigned short* Wp = (unsigned short*)((char*)d_ws + 4096);

    hipMemsetAsync(d_ws, 0, 16, stream);
    wnorm_kernel<<<2, 256, 0, stream>>>(W, wn);
    prep_kernel<<<32, 256, 0, stream>>>(W, Wp);
    vq_main<<<NBLK, 256, 0, stream>>>(Z, W, Wp, wn, out, diffsum);
    diff_kernel<<<1, 64, 0, stream>>>(diffsum, out);
}

// Round 4
// 135.879 us; speedup vs baseline: 8.0891x; 1.1969x over previous
//
#include <hip/hip_runtime.h>
#include <float.h>

// Quantize: z [8,4096,512] f32, embed_w [512,128] f32, GROUPS=4
// flat = z.reshape(131072,128); dist to 512 codes; argmin; gather; MSE scalar.
// d_out (f32): z_q_st [16777216], diff [1], ind [131072] (as float).
//
// bf16 split-precision MFMA (hi*hi + lo*hi + hi*lo), W preconverted+preswizzled,
// double-buffered 32-code chunks (small LDS -> 4 blocks/CU), fp64 exact
// refinement for near-tie rows (ballot-dispatched).

typedef __attribute__((ext_vector_type(8))) short short8;
typedef __attribute__((ext_vector_type(4))) float f32x4;

constexpr int Dn = 128;
constexpr int K  = 512;
constexpr long long Mrows = 131072;
constexpr int RPB  = 128;                    // rows per block (4 waves x 32)
constexpr int NBLK = (int)(Mrows / RPB);     // 1024
constexpr int CHUNK = 32;                    // codes per LDS chunk
constexpr int NCH   = K / CHUNK;             // 16
constexpr float TAU_A = 0.004f;              // score-margin flag threshold (dist margin 0.008)

constexpr size_t ZQ_SIZE  = (size_t)Mrows * Dn;
constexpr size_t DIFF_OFF = ZQ_SIZE;
constexpr size_t IND_OFF  = ZQ_SIZE + 1;

__device__ inline unsigned short f2bf(float f) {    // RNE float->bf16
    unsigned u = __builtin_bit_cast(unsigned, f);
    u += 0x7FFFu + ((u >> 16) & 1u);
    return (unsigned short)(u >> 16);
}
__device__ inline float bf2f(unsigned short s) {
    unsigned u = ((unsigned)s) << 16;
    return __builtin_bit_cast(float, u);
}

__device__ inline void gload_lds16(const void* g, void* l) {
    __builtin_amdgcn_global_load_lds(
        (const __attribute__((address_space(1))) unsigned int*)g,
        (__attribute__((address_space(3))) unsigned int*)l,
        16, 0, 0);
}

__global__ void wnorm_kernel(const float* __restrict__ W, float* __restrict__ wn2) {
    int k = blockIdx.x * blockDim.x + threadIdx.x;
    if (k < K) {
        double s = 0.0;
        const float* w = W + (size_t)k * Dn;
        #pragma unroll 4
        for (int i = 0; i < Dn; ++i) { double v = (double)w[i]; s += v * v; }
        wn2[k] = (float)(-0.5 * s);
    }
}

// W -> bf16 hi/lo, pre-swizzled granule order.
// Per chunk ch (32 codes): 16 KB = [hi 8KB][lo 8KB].
// Hi-region granule index G = code_l*16 + gs holds physical granule
// g = gs ^ (code_l & 7) of that code's row (8 bf16 per 16B granule).
__global__ void prep_kernel(const float* __restrict__ W, unsigned short* __restrict__ Wp) {
    int t = blockIdx.x * 256 + threadIdx.x;  // 0..8191 (512 codes * 16 granules)
    int code   = t >> 4;
    int gs     = t & 15;
    int ch     = code >> 5;
    int code_l = code & 31;
    int g      = gs ^ (code_l & 7);
    const float* src = W + (size_t)code * Dn + g * 8;
    ushort4 h[2], l[2];
    #pragma unroll
    for (int half = 0; half < 2; ++half) {
        float4 v = *(const float4*)(src + half * 4);
        float vv[4] = {v.x, v.y, v.z, v.w};
        unsigned short* hp = (unsigned short*)&h[half];
        unsigned short* lp = (unsigned short*)&l[half];
        #pragma unroll
        for (int e = 0; e < 4; ++e) {
            unsigned short hs = f2bf(vv[e]);
            hp[e] = hs;
            lp[e] = f2bf(vv[e] - bf2f(hs));
        }
    }
    size_t base = (size_t)ch * 8192 + (size_t)(code_l * 16 + gs) * 8;   // ushort units
    *(ushort4*)(Wp + base)            = h[0];
    *(ushort4*)(Wp + base + 4)        = h[1];
    *(ushort4*)(Wp + base + 4096)     = l[0];
    *(ushort4*)(Wp + base + 4096 + 4) = l[1];
}

__global__ __launch_bounds__(256, 4) void vq_main(
        const float* __restrict__ Z, const float* __restrict__ W,
        const unsigned short* __restrict__ Wp, const float* __restrict__ wn2,
        float* __restrict__ out, double* __restrict__ diffsum) {
    __shared__ __align__(16) char Wbuf[2][16384];   // double-buffered 32-code chunk
    __shared__ float wn2_s[K];
    __shared__ int   sIdx[RPB];
    __shared__ int   sFlag[RPB];
    __shared__ float xn_s[RPB];
    __shared__ float wpart[4];

    const int tid  = threadIdx.x;
    const int w    = tid >> 6;
    const int lane = tid & 63;
    const int lm   = lane & 15;        // A row / B col within 16-tile
    const int lg   = lane >> 4;        // k-block (0..3)
    const size_t row0 = (size_t)blockIdx.x * RPB;

    // ---- staging: pure DMA (layout pre-swizzled in Wp) ----
    auto stage = [&](int bi, int ch) {
        const char* gsrc = (const char*)Wp + (size_t)ch * 16384;
        char* lb = &Wbuf[bi][0];
        #pragma unroll
        for (int it = 0; it < 4; ++it) {
            const int gb = (w * 4 + it) * 64;            // wave-uniform granule base
            gload_lds16(gsrc + (size_t)(gb + lane) * 16, lb + (size_t)gb * 16);
        }
    };
    stage(0, 0);                        // issue chunk 0 DMA first

    // ---- X fragments (hi/lo bf16) + exact row norms, in registers ----
    short8 ahi[2][4], alo[2][4];
    #pragma unroll
    for (int r = 0; r < 2; ++r) {
        const size_t grow = row0 + (size_t)w * 32 + r * 16 + lm;
        float s2 = 0.f;
        #pragma unroll
        for (int ks = 0; ks < 4; ++ks) {
            const float* xp = Z + grow * Dn + ks * 32 + lg * 8;
            float4 x0 = *(const float4*)xp;
            float4 x1 = *(const float4*)(xp + 4);
            float xv[8] = {x0.x, x0.y, x0.z, x0.w, x1.x, x1.y, x1.z, x1.w};
            #pragma unroll
            for (int j = 0; j < 8; ++j) {
                unsigned short hs = f2bf(xv[j]);
                ahi[r][ks][j] = (short)hs;
                alo[r][ks][j] = (short)f2bf(xv[j] - bf2f(hs));
                s2 += xv[j] * xv[j];
            }
        }
        s2 += __shfl_xor(s2, 16);
        s2 += __shfl_xor(s2, 32);
        if (lg == 0) xn_s[w * 32 + r * 16 + lm] = s2;
    }
    // wn2 -> LDS (broadcast table)
    #pragma unroll
    for (int i = 0; i < K / 256; ++i) wn2_s[tid + i * 256] = wn2[tid + i * 256];

    // max-tracking of a = dot - 0.5*||w||^2  (argmin dist == argmax a)
    float m1[2][4], m2[2][4];
    int   i1[2][4];
    #pragma unroll
    for (int r = 0; r < 2; ++r)
        #pragma unroll
        for (int j = 0; j < 4; ++j) { m1[r][j] = -FLT_MAX; m2[r][j] = -FLT_MAX; i1[r][j] = 0; }

    asm volatile("s_waitcnt vmcnt(0)" ::: "memory");
    __syncthreads();

    for (int ch = 0; ch < NCH; ++ch) {
        const int cur = ch & 1;
        if (ch + 1 < NCH) stage(cur ^ 1, ch + 1);     // prefetch next chunk (async)
        const char* buf = &Wbuf[cur][0];

        #pragma unroll
        for (int t = 0; t < 2; ++t) {
            const int code_l = t * 16 + lm;
            const int c = ch * CHUNK + code_l;
            const float cinit = wn2_s[c];             // -0.5*||w||^2
            short8 bhi[4], blo[4];
            #pragma unroll
            for (int ks = 0; ks < 4; ++ks) {
                const int off = code_l * 256 + ((((ks << 2) + lg) ^ (code_l & 7)) << 4);
                bhi[ks] = *(const short8*)(buf + off);
                blo[ks] = *(const short8*)(buf + 8192 + off);
            }
            f32x4 acc[2];
            #pragma unroll
            for (int r = 0; r < 2; ++r) acc[r] = (f32x4){cinit, cinit, cinit, cinit};
            #pragma unroll
            for (int ks = 0; ks < 4; ++ks) {
                #pragma unroll
                for (int r = 0; r < 2; ++r) {
                    acc[r] = __builtin_amdgcn_mfma_f32_16x16x32_bf16(ahi[r][ks], bhi[ks], acc[r], 0, 0, 0);
                    acc[r] = __builtin_amdgcn_mfma_f32_16x16x32_bf16(alo[r][ks], bhi[ks], acc[r], 0, 0, 0);
                    acc[r] = __builtin_amdgcn_mfma_f32_16x16x32_bf16(ahi[r][ks], blo[ks], acc[r], 0, 0, 0);
                }
            }
            #pragma unroll
            for (int r = 0; r < 2; ++r) {
                #pragma unroll
                for (int j = 0; j < 4; ++j) {
                    const float a = acc[r][j];
                    m2[r][j] = __builtin_amdgcn_fmed3f(a, m1[r][j], m2[r][j]);
                    const bool gt = a > m1[r][j];
                    m1[r][j] = fmaxf(m1[r][j], a);
                    i1[r][j] = gt ? c : i1[r][j];
                }
            }
        }
        asm volatile("s_waitcnt vmcnt(0)" ::: "memory");  // next chunk landed
        __syncthreads();                                   // all waves done with buf
    }

    // ---- reduce (m1, idx, m2) across the 16 col-lanes ----
    #pragma unroll
    for (int sft = 1; sft < 16; sft <<= 1) {
        #pragma unroll
        for (int r = 0; r < 2; ++r) {
            #pragma unroll
            for (int j = 0; j < 4; ++j) {
                float o1 = __shfl_xor(m1[r][j], sft);
                float o2 = __shfl_xor(m2[r][j], sft);
                int   oi = __shfl_xor(i1[r][j], sft);
                if (o1 > m1[r][j] || (o1 == m1[r][j] && oi < i1[r][j])) {
                    m2[r][j] = fmaxf(m1[r][j], o2);
                    m1[r][j] = o1;
                    i1[r][j] = oi;
                } else {
                    m2[r][j] = fmaxf(m2[r][j], o1);
                }
            }
        }
    }

    float psum = 0.f;
    if (lm == 0) {
        #pragma unroll
        for (int r = 0; r < 2; ++r) {
            #pragma unroll
            for (int j = 0; j < 4; ++j) {
                const int row = w * 32 + r * 16 + lg * 4 + j;   // C row = lg*4 + reg
                sIdx[row]  = i1[r][j];
                sFlag[row] = (m1[r][j] - m2[r][j] < TAU_A) ? 1 : 0;
                // dist^2 = ||x||^2 - 2*a
                psum += xn_s[row] - 2.f * m1[r][j];
            }
        }
    }
    __syncthreads();

    // ---- fp64 exact refinement of near-tie rows (ballot-dispatched, rare) ----
    {
        const int rbase = w * 32;
        unsigned long long fl = __ballot(lane < 32 && sFlag[rbase + (lane & 31)]);
        while (fl) {
            const int rr = rbase + (__ffsll(fl) - 1);
            fl &= fl - 1;
            const float* xp = Z + (row0 + rr) * Dn;
            double best = 1e300; int bi = 0;
            for (int jj = 0; jj < 8; ++jj) {
                const int k = lane + 64 * jj;
                const float* wp = W + (size_t)k * Dn;
                double s = 0.0;
                for (int i = 0; i < Dn; ++i) {
                    double dx = (double)xp[i] - (double)wp[i];
                    s += dx * dx;
                }
                if (s < best) { best = s; bi = k; }
            }
            #pragma unroll
            for (int sft = 1; sft < 64; sft <<= 1) {
                double ob = __shfl_xor(best, sft);
                int    ok = __shfl_xor(bi, sft);
                if (ob < best || (ob == best && ok < bi)) { best = ob; bi = ok; }
            }
            if (lane == 0) sIdx[rr] = bi;
        }
    }
    __syncthreads();

    // ---- epilogue: z_q_st == W[ind] gather; indices; diff partial ----
    #pragma unroll
    for (int it = 0; it < 16; ++it) {
        int f4i = tid + it * 256;              // 0..4095
        int row = f4i >> 5, cq = f4i & 31;
        int ind = sIdx[row];
        float4 wv = ((const float4*)(W + (size_t)ind * Dn))[cq];
        ((float4*)(out + (row0 + row) * Dn))[cq] = wv;
    }
    if (tid < RPB) out[IND_OFF + row0 + tid] = (float)sIdx[tid];

    #pragma unroll
    for (int sft = 1; sft < 64; sft <<= 1) psum += __shfl_xor(psum, sft);
    if (lane == 0) wpart[w] = psum;
    __syncthreads();
    if (tid == 0) {
        double t = (double)wpart[0] + (double)wpart[1] + (double)wpart[2] + (double)wpart[3];
        atomicAdd(diffsum, t);
    }
}

__global__ void diff_kernel(const double* __restrict__ diffsum, float* __restrict__ out) {
    if (threadIdx.x == 0 && blockIdx.x == 0) {
        // KLD_SCALE * (COMMITMENT_COST + 1) * mean = 12.5 * mean
        out[DIFF_OFF] = (float)(12.5 * diffsum[0] / (double)ZQ_SIZE);
    }
}

extern "C" void kernel_launch(void* const* d_in, const int* in_sizes, int n_in,
                              void* d_out, int out_size, void* d_ws, size_t ws_size,
                              hipStream_t stream) {
    (void)in_sizes; (void)n_in; (void)out_size; (void)ws_size;
    const float* Z = (const float*)d_in[0];
    const float* W = (const float*)d_in[1];
    float* out = (float*)d_out;
    // ws layout: [0,8) diffsum double; [16,2064) wn2 f32[512]; [4096, +256KB) Wp
    double* diffsum = (double*)d_ws;
    float* wn2 = (float*)((char*)d_ws + 16);
    unsigned short* Wp = (unsigned short*)((char*)d_ws + 4096);

    hipMemsetAsync(d_ws, 0, 16, stream);
    wnorm_kernel<<<2, 256, 0, stream>>>(W, wn2);
    prep_kernel<<<32, 256, 0, stream>>>(W, Wp);
    vq_main<<<NBLK, 256, 0, stream>>>(Z, W, Wp, wn2, out, diffsum);
    diff_kernel<<<1, 64, 0, stream>>>(diffsum, out);
}